// Round 1
// baseline (509.371 us; speedup 1.0000x reference)
//
#include <hip/hip_runtime.h>
#include <hip/hip_bf16.h>
#include <math.h>

#define NFEAT 128
#define NCLS 64

// ---------- graph build ----------

__global__ void count_kernel(const int* __restrict__ dst, int* __restrict__ cnt, int E) {
    int e = blockIdx.x * blockDim.x + threadIdx.x;
    if (e < E) atomicAdd(&cnt[dst[e]], 1);
}

// single-block exclusive scan: row_ptr[0]=0, row_ptr[i+1]=sum(cnt[0..i])
__global__ void scan_kernel(const int* __restrict__ cnt, int* __restrict__ row_ptr, int n) {
    __shared__ int lds[1024];
    const int tid = threadIdx.x;
    int carry = 0;
    for (int base = 0; base < n; base += 1024) {
        int i = base + tid;
        int v = (i < n) ? cnt[i] : 0;
        __syncthreads();               // protect lds from previous chunk's reads
        lds[tid] = v;
        __syncthreads();
        for (int off = 1; off < 1024; off <<= 1) {
            int t = (tid >= off) ? lds[tid - off] : 0;
            __syncthreads();
            lds[tid] += t;
            __syncthreads();
        }
        if (i < n) row_ptr[i + 1] = carry + lds[tid];
        carry += lds[1023];            // broadcast read, valid after last sync
    }
    if (tid == 0) row_ptr[0] = 0;
}

__global__ void init_kernel(const int* __restrict__ cnt, const int* __restrict__ row_ptr,
                            int* __restrict__ cursor, float* __restrict__ dinv, int N) {
    int i = blockIdx.x * blockDim.x + threadIdx.x;
    if (i < N) {
        cursor[i] = row_ptr[i];
        dinv[i] = rsqrtf((float)cnt[i] + 1.0f);   // +1 = self-loop
    }
}

__global__ void scatter_kernel(const int* __restrict__ src, const int* __restrict__ dst,
                               int* __restrict__ cursor, int* __restrict__ csr, int E) {
    int e = blockIdx.x * blockDim.x + threadIdx.x;
    if (e < E) {
        int pos = atomicAdd(&cursor[dst[e]], 1);
        csr[pos] = src[e];
    }
}

// ---------- hop 1: x -> x1 ----------
// one 128-thread block per node; thread f handles feature f
__global__ __launch_bounds__(128) void hop1_kernel(const float* __restrict__ x,
                                                   const float* __restrict__ dinv,
                                                   const int* __restrict__ row_ptr,
                                                   const int* __restrict__ csr,
                                                   float* __restrict__ x1, int N) {
    int i = blockIdx.x;
    if (i >= N) return;
    int f = threadIdx.x;
    float di = dinv[i];
    float acc = di * x[(size_t)i * NFEAT + f];     // self loop (norm = di*di, di factored out)
    int ks = row_ptr[i], ke = row_ptr[i + 1];
    for (int k = ks; k < ke; ++k) {
        int j = csr[k];                             // same-address broadcast across wave
        acc += dinv[j] * x[(size_t)j * NFEAT + f];  // coalesced 512B row read
    }
    x1[(size_t)i * NFEAT + f] = di * acc;
}

// ---------- hop 2 fused with linear + log_softmax ----------
// 256 threads = 4 nodes x 64 lanes. W staged in LDS with stride 129 (bank-conflict pad).
__global__ __launch_bounds__(256) void hop2_cls_kernel(const float* __restrict__ x1,
                                                       const float* __restrict__ dinv,
                                                       const int* __restrict__ row_ptr,
                                                       const int* __restrict__ csr,
                                                       const float* __restrict__ W,
                                                       const float* __restrict__ b,
                                                       float* __restrict__ out, int N) {
    __shared__ float Wl[NCLS * (NFEAT + 1)];   // stride 129: lane c reads bank (c+f)%32 -> 2-way (free)
    __shared__ float bl[NCLS];
    __shared__ float h[4][NFEAT];

    const int tid = threadIdx.x;
    for (int t = tid; t < NCLS * NFEAT; t += 256) {
        int r = t >> 7, c = t & 127;
        Wl[r * (NFEAT + 1) + c] = W[t];
    }
    if (tid < NCLS) bl[tid] = b[tid];

    const int s = tid >> 6;          // sub-block (node slot), one wave each
    const int lane = tid & 63;
    const int i = blockIdx.x * 4 + s;

    if (i < N) {
        float di = dinv[i];
        float a0 = di * x1[(size_t)i * NFEAT + lane];
        float a1 = di * x1[(size_t)i * NFEAT + 64 + lane];
        int ks = row_ptr[i], ke = row_ptr[i + 1];
        for (int k = ks; k < ke; ++k) {
            int j = csr[k];
            float dj = dinv[j];
            a0 += dj * x1[(size_t)j * NFEAT + lane];
            a1 += dj * x1[(size_t)j * NFEAT + 64 + lane];
        }
        h[s][lane] = di * a0;
        h[s][lane + 64] = di * a1;
    }
    __syncthreads();

    if (i < N) {
        float dot = bl[lane];
        const float* hr = h[s];                    // broadcast across lanes
        const float* wr = &Wl[lane * (NFEAT + 1)];
        #pragma unroll 8
        for (int f = 0; f < NFEAT; ++f) dot = fmaf(hr[f], wr[f], dot);

        float m = dot;
        for (int o = 32; o > 0; o >>= 1) m = fmaxf(m, __shfl_xor(m, o));
        float ex = __expf(dot - m);
        float se = ex;
        for (int o = 32; o > 0; o >>= 1) se += __shfl_xor(se, o);
        out[(size_t)i * NCLS + lane] = dot - m - logf(se);
    }
}

// ---------- launch ----------

static inline size_t align256(size_t v) { return (v + 255) & ~(size_t)255; }

extern "C" void kernel_launch(void* const* d_in, const int* in_sizes, int n_in,
                              void* d_out, int out_size, void* d_ws, size_t ws_size,
                              hipStream_t stream) {
    const float* x  = (const float*)d_in[0];
    const int*   ei = (const int*)d_in[1];
    const float* W  = (const float*)d_in[2];
    const float* b  = (const float*)d_in[3];
    float* out = (float*)d_out;

    const int N = in_sizes[0] / NFEAT;   // 50000
    const int E = in_sizes[1] / 2;       // 800000
    const int* src = ei;
    const int* dst = ei + E;

    char* ws = (char*)d_ws;
    size_t o = 0;
    int*   cnt     = (int*)(ws + o);   o += align256((size_t)N * 4);
    float* dinv    = (float*)(ws + o); o += align256((size_t)N * 4);
    int*   row_ptr = (int*)(ws + o);   o += align256((size_t)(N + 1) * 4);
    int*   cursor  = (int*)(ws + o);   o += align256((size_t)N * 4);
    int*   csr     = (int*)(ws + o);   o += align256((size_t)E * 4);
    float* x1      = (float*)(ws + o); o += (size_t)N * NFEAT * 4;

    hipMemsetAsync(cnt, 0, (size_t)N * 4, stream);
    count_kernel<<<(E + 255) / 256, 256, 0, stream>>>(dst, cnt, E);
    scan_kernel<<<1, 1024, 0, stream>>>(cnt, row_ptr, N);
    init_kernel<<<(N + 255) / 256, 256, 0, stream>>>(cnt, row_ptr, cursor, dinv, N);
    scatter_kernel<<<(E + 255) / 256, 256, 0, stream>>>(src, dst, cursor, csr, E);
    hop1_kernel<<<N, 128, 0, stream>>>(x, dinv, row_ptr, csr, x1, N);
    hop2_cls_kernel<<<(N + 3) / 4, 256, 0, stream>>>(x1, dinv, row_ptr, csr, W, b, out, N);
}

// Round 2
// 301.630 us; speedup vs baseline: 1.6887x; 1.6887x over previous
//
#include <hip/hip_runtime.h>
#include <hip/hip_bf16.h>
#include <math.h>

#define NFEAT 128
#define NF4   32            // NFEAT / 4
#define NCLS  64
#define WPAD  132           // W row stride in floats (float4-aligned pad)

__device__ __forceinline__ void fma4(float4& a, float s, const float4 v) {
    a.x = fmaf(s, v.x, a.x); a.y = fmaf(s, v.y, a.y);
    a.z = fmaf(s, v.z, a.z); a.w = fmaf(s, v.w, a.w);
}
__device__ __forceinline__ void add4(float4& a, const float4 v) {
    a.x += v.x; a.y += v.y; a.z += v.z; a.w += v.w;
}

// ---------- graph build ----------

__global__ void count_kernel(const int* __restrict__ dst, int* __restrict__ cnt, int E) {
    int e = blockIdx.x * blockDim.x + threadIdx.x;
    if (e < E) atomicAdd(&cnt[dst[e]], 1);
}

// 3-kernel device-wide exclusive scan over cnt -> row_ptr/cursor (+ dinv)
__global__ void scan_local(const int* __restrict__ cnt, int* __restrict__ row_ptr,
                           int* __restrict__ bsums, int n) {
    __shared__ int lds[256];
    const int tid = threadIdx.x;
    int i = blockIdx.x * 256 + tid;
    int v = (i < n) ? cnt[i] : 0;
    lds[tid] = v;
    __syncthreads();
    for (int off = 1; off < 256; off <<= 1) {
        int t = (tid >= off) ? lds[tid - off] : 0;
        __syncthreads();
        lds[tid] += t;
        __syncthreads();
    }
    if (i < n) row_ptr[i + 1] = lds[tid];          // local inclusive scan
    if (tid == 255) bsums[blockIdx.x] = lds[255];  // block total
}

__global__ void scan_bsums(int* __restrict__ bsums, int nb) {  // nb <= 256
    __shared__ int lds[256];
    const int tid = threadIdx.x;
    lds[tid] = (tid < nb) ? bsums[tid] : 0;
    __syncthreads();
    for (int off = 1; off < 256; off <<= 1) {
        int t = (tid >= off) ? lds[tid - off] : 0;
        __syncthreads();
        lds[tid] += t;
        __syncthreads();
    }
    if (tid < nb) bsums[tid] = lds[tid];           // inclusive totals
}

__global__ void scan_finalize(const int* __restrict__ cnt, const int* __restrict__ bsums,
                              int* __restrict__ row_ptr, int* __restrict__ cursor,
                              float* __restrict__ dinv, int n) {
    const int tid = threadIdx.x;
    int i = blockIdx.x * 256 + tid;
    if (i < n) {
        int off = blockIdx.x ? bsums[blockIdx.x - 1] : 0;
        int incl = row_ptr[i + 1] + off;
        row_ptr[i + 1] = incl;
        int c = cnt[i];
        cursor[i] = incl - c;
        dinv[i] = rsqrtf((float)c + 1.0f);         // +1 self-loop
        if (i == 0) row_ptr[0] = 0;
    }
}

__global__ void scatter_kernel(const int* __restrict__ src, const int* __restrict__ dst,
                               int* __restrict__ cursor, int* __restrict__ csr, int E) {
    int e = blockIdx.x * blockDim.x + threadIdx.x;
    if (e < E) {
        int pos = atomicAdd(&cursor[dst[e]], 1);
        csr[pos] = src[e];
    }
}

// ---------- hop 1: y1[i] = dinv[i]^2 * (sum_j dinv[j] x[j] + dinv[i] x[i]) ----------
// 1 wave per node; lanes 0-31 = even edges, 32-63 = odd edges; float4 per lane.
__global__ __launch_bounds__(256) void hop1_kernel(const float* __restrict__ x,
                                                   const float* __restrict__ dinv,
                                                   const int* __restrict__ row_ptr,
                                                   const int* __restrict__ csr,
                                                   float* __restrict__ y1, int N) {
    const int tid = threadIdx.x;
    const int w = tid >> 6, lane = tid & 63;
    const int i = blockIdx.x * 4 + w;
    if (i >= N) return;                            // wave-uniform, no barriers here
    const int half = lane >> 5;
    const int q = lane & 31;
    const float4* X = (const float4*)x;

    float4 acc = {0.f, 0.f, 0.f, 0.f};
    int ks = row_ptr[i], ke = row_ptr[i + 1];
    int k = ks;
    for (; k + 8 <= ke; k += 8) {                  // 4 edges per half in flight
        int j0 = csr[k + half];
        int j1 = csr[k + 2 + half];
        int j2 = csr[k + 4 + half];
        int j3 = csr[k + 6 + half];
        float4 v0 = X[(size_t)j0 * NF4 + q];
        float4 v1 = X[(size_t)j1 * NF4 + q];
        float4 v2 = X[(size_t)j2 * NF4 + q];
        float4 v3 = X[(size_t)j3 * NF4 + q];
        float d0 = dinv[j0], d1 = dinv[j1], d2 = dinv[j2], d3 = dinv[j3];
        fma4(acc, d0, v0); fma4(acc, d1, v1); fma4(acc, d2, v2); fma4(acc, d3, v3);
    }
    for (; k + 2 <= ke; k += 2) {
        int j = csr[k + half];
        float4 v = X[(size_t)j * NF4 + q];
        fma4(acc, dinv[j], v);
    }
    float di = dinv[i];
    if (k < ke && half == 0) {                     // odd tail edge
        int j = csr[k];
        fma4(acc, dinv[j], X[(size_t)j * NF4 + q]);
    }
    if (half == 1) fma4(acc, di, X[(size_t)i * NF4 + q]);   // self term

    acc.x += __shfl_xor(acc.x, 32);
    acc.y += __shfl_xor(acc.y, 32);
    acc.z += __shfl_xor(acc.z, 32);
    acc.w += __shfl_xor(acc.w, 32);

    if (half == 0) {
        float s = di * di;                         // pre-scale for hop2 (y1 = dinv * x1)
        float4 r;
        r.x = s * acc.x; r.y = s * acc.y; r.z = s * acc.z; r.w = s * acc.w;
        ((float4*)y1)[(size_t)i * NF4 + q] = r;
    }
}

// ---------- hop 2 fused with linear + log_softmax ----------
// 512 threads = 8 waves = 8 nodes. Pure unweighted gather of y1 (dinv folded in).
__global__ __launch_bounds__(512) void hop2_cls_kernel(const float* __restrict__ y1,
                                                       const float* __restrict__ dinv,
                                                       const int* __restrict__ row_ptr,
                                                       const int* __restrict__ csr,
                                                       const float* __restrict__ W,
                                                       const float* __restrict__ b,
                                                       float* __restrict__ out, int N) {
    __shared__ __align__(16) float Wl[NCLS * WPAD];   // 33 KB, padded rows
    __shared__ float bl[NCLS];
    __shared__ __align__(16) float h[8][NFEAT];

    const int tid = threadIdx.x;
    for (int t = tid; t < NCLS * NFEAT; t += 512) {
        int r = t >> 7, c = t & 127;
        Wl[r * WPAD + c] = W[t];
    }
    if (tid < NCLS) bl[tid] = b[tid];

    const int w = tid >> 6, lane = tid & 63;
    const int i = blockIdx.x * 8 + w;
    const int half = lane >> 5;
    const int q = lane & 31;
    const float4* Y = (const float4*)y1;

    if (i < N) {
        float4 acc = {0.f, 0.f, 0.f, 0.f};
        int ks = row_ptr[i], ke = row_ptr[i + 1];
        int k = ks;
        for (; k + 8 <= ke; k += 8) {
            int j0 = csr[k + half];
            int j1 = csr[k + 2 + half];
            int j2 = csr[k + 4 + half];
            int j3 = csr[k + 6 + half];
            float4 v0 = Y[(size_t)j0 * NF4 + q];
            float4 v1 = Y[(size_t)j1 * NF4 + q];
            float4 v2 = Y[(size_t)j2 * NF4 + q];
            float4 v3 = Y[(size_t)j3 * NF4 + q];
            add4(acc, v0); add4(acc, v1); add4(acc, v2); add4(acc, v3);
        }
        for (; k + 2 <= ke; k += 2) {
            add4(acc, Y[(size_t)csr[k + half] * NF4 + q]);
        }
        if (k < ke && half == 0) add4(acc, Y[(size_t)csr[k] * NF4 + q]);
        if (half == 1) add4(acc, Y[(size_t)i * NF4 + q]);    // self term

        acc.x += __shfl_xor(acc.x, 32);
        acc.y += __shfl_xor(acc.y, 32);
        acc.z += __shfl_xor(acc.z, 32);
        acc.w += __shfl_xor(acc.w, 32);

        if (half == 0) {
            float di = dinv[i];
            float4 r;
            r.x = di * acc.x; r.y = di * acc.y; r.z = di * acc.z; r.w = di * acc.w;
            ((float4*)h[w])[q] = r;
        }
    }
    __syncthreads();

    if (i < N) {
        float dot = bl[lane];
        const float4* hr = (const float4*)h[w];                  // broadcast
        const float4* wr = (const float4*)(Wl + lane * WPAD);    // stride 132: clean banking
        #pragma unroll
        for (int t = 0; t < NF4; ++t) {
            float4 hv = hr[t], wv = wr[t];
            dot = fmaf(hv.x, wv.x, dot); dot = fmaf(hv.y, wv.y, dot);
            dot = fmaf(hv.z, wv.z, dot); dot = fmaf(hv.w, wv.w, dot);
        }
        float m = dot;
        for (int o = 32; o > 0; o >>= 1) m = fmaxf(m, __shfl_xor(m, o));
        float ex = __expf(dot - m);
        float se = ex;
        for (int o = 32; o > 0; o >>= 1) se += __shfl_xor(se, o);
        out[(size_t)i * NCLS + lane] = dot - m - logf(se);
    }
}

// ---------- launch ----------

static inline size_t align256(size_t v) { return (v + 255) & ~(size_t)255; }

extern "C" void kernel_launch(void* const* d_in, const int* in_sizes, int n_in,
                              void* d_out, int out_size, void* d_ws, size_t ws_size,
                              hipStream_t stream) {
    const float* x  = (const float*)d_in[0];
    const int*   ei = (const int*)d_in[1];
    const float* W  = (const float*)d_in[2];
    const float* b  = (const float*)d_in[3];
    float* out = (float*)d_out;

    const int N = in_sizes[0] / NFEAT;   // 50000
    const int E = in_sizes[1] / 2;       // 800000
    const int* src = ei;
    const int* dst = ei + E;
    const int NB = (N + 255) / 256;      // 196 scan blocks

    char* ws = (char*)d_ws;
    size_t o = 0;
    int*   cnt     = (int*)(ws + o);   o += align256((size_t)N * 4);
    float* dinv    = (float*)(ws + o); o += align256((size_t)N * 4);
    int*   row_ptr = (int*)(ws + o);   o += align256((size_t)(N + 1) * 4);
    int*   cursor  = (int*)(ws + o);   o += align256((size_t)N * 4);
    int*   bsums   = (int*)(ws + o);   o += align256(256 * 4);
    int*   csr     = (int*)(ws + o);   o += align256((size_t)E * 4);
    float* y1      = (float*)(ws + o); o += (size_t)N * NFEAT * 4;

    hipMemsetAsync(cnt, 0, (size_t)N * 4, stream);
    count_kernel<<<(E + 255) / 256, 256, 0, stream>>>(dst, cnt, E);
    scan_local<<<NB, 256, 0, stream>>>(cnt, row_ptr, bsums, N);
    scan_bsums<<<1, 256, 0, stream>>>(bsums, NB);
    scan_finalize<<<NB, 256, 0, stream>>>(cnt, bsums, row_ptr, cursor, dinv, N);
    scatter_kernel<<<(E + 255) / 256, 256, 0, stream>>>(src, dst, cursor, csr, E);
    hop1_kernel<<<(N + 3) / 4, 256, 0, stream>>>(x, dinv, row_ptr, csr, y1, N);
    hop2_cls_kernel<<<(N + 7) / 8, 512, 0, stream>>>(y1, dinv, row_ptr, csr, W, b, out, N);
}

// Round 3
// 274.593 us; speedup vs baseline: 1.8550x; 1.0985x over previous
//
#include <hip/hip_runtime.h>
#include <hip/hip_bf16.h>
#include <hip/hip_fp16.h>
#include <math.h>

#define NFEAT 128
#define NCLS  64
#define WPAD  132           // W row stride in floats (float4-aligned pad)
#define RQ    16            // uint4 per fp16 row (128*2/16)

// ---------- helpers ----------

__device__ __forceinline__ void accum_h8(float acc[8], uint4 v) {
    union { uint4 u; __half2 h[4]; } c; c.u = v;
    #pragma unroll
    for (int t = 0; t < 4; ++t) {
        float2 f = __half22float2(c.h[t]);
        acc[2 * t]     += f.x;
        acc[2 * t + 1] += f.y;
    }
}

// ---------- graph build ----------

__global__ void count_kernel(const int* __restrict__ dst, int* __restrict__ cnt, int E) {
    int e4 = blockIdx.x * blockDim.x + threadIdx.x;     // 4 edges per thread
    if (e4 * 4 + 3 < E) {
        int4 d = ((const int4*)dst)[e4];
        atomicAdd(&cnt[d.x], 1); atomicAdd(&cnt[d.y], 1);
        atomicAdd(&cnt[d.z], 1); atomicAdd(&cnt[d.w], 1);
    } else {
        for (int e = e4 * 4; e < E; ++e) atomicAdd(&cnt[dst[e]], 1);
    }
}

// 3-kernel device-wide exclusive scan over cnt -> row_ptr/cursor (+ dinv)
__global__ void scan_local(const int* __restrict__ cnt, int* __restrict__ row_ptr,
                           int* __restrict__ bsums, int n) {
    __shared__ int lds[256];
    const int tid = threadIdx.x;
    int i = blockIdx.x * 256 + tid;
    int v = (i < n) ? cnt[i] : 0;
    lds[tid] = v;
    __syncthreads();
    for (int off = 1; off < 256; off <<= 1) {
        int t = (tid >= off) ? lds[tid - off] : 0;
        __syncthreads();
        lds[tid] += t;
        __syncthreads();
    }
    if (i < n) row_ptr[i + 1] = lds[tid];
    if (tid == 255) bsums[blockIdx.x] = lds[255];
}

__global__ void scan_bsums(int* __restrict__ bsums, int nb) {  // nb <= 256
    __shared__ int lds[256];
    const int tid = threadIdx.x;
    lds[tid] = (tid < nb) ? bsums[tid] : 0;
    __syncthreads();
    for (int off = 1; off < 256; off <<= 1) {
        int t = (tid >= off) ? lds[tid - off] : 0;
        __syncthreads();
        lds[tid] += t;
        __syncthreads();
    }
    if (tid < nb) bsums[tid] = lds[tid];
}

__global__ void scan_finalize(const int* __restrict__ cnt, const int* __restrict__ bsums,
                              int* __restrict__ row_ptr, int* __restrict__ cursor,
                              float* __restrict__ dinv, int n) {
    int i = blockIdx.x * 256 + threadIdx.x;
    if (i < n) {
        int off = blockIdx.x ? bsums[blockIdx.x - 1] : 0;
        int incl = row_ptr[i + 1] + off;
        row_ptr[i + 1] = incl;
        int c = cnt[i];
        cursor[i] = incl - c;
        dinv[i] = rsqrtf((float)c + 1.0f);   // +1 self-loop
        if (i == 0) row_ptr[0] = 0;
    }
}

__global__ void scatter_kernel(const int* __restrict__ src, const int* __restrict__ dst,
                               int* __restrict__ cursor, int* __restrict__ csr, int E) {
    int e4 = blockIdx.x * blockDim.x + threadIdx.x;
    if (e4 * 4 + 3 < E) {
        int4 s = ((const int4*)src)[e4];
        int4 d = ((const int4*)dst)[e4];
        csr[atomicAdd(&cursor[d.x], 1)] = s.x;
        csr[atomicAdd(&cursor[d.y], 1)] = s.y;
        csr[atomicAdd(&cursor[d.z], 1)] = s.z;
        csr[atomicAdd(&cursor[d.w], 1)] = s.w;
    } else {
        for (int e = e4 * 4; e < E; ++e)
            csr[atomicAdd(&cursor[dst[e]], 1)] = src[e];
    }
}

// ---------- prep: xh[j] = dinv[j] * x[j] as fp16 ----------
__global__ void prep_kernel(const float* __restrict__ x, const float* __restrict__ dinv,
                            __half* __restrict__ xh, int total4) {   // total4 = N*32
    int idx = blockIdx.x * blockDim.x + threadIdx.x;
    if (idx < total4) {
        float d = dinv[idx >> 5];                 // 32 quads per node
        float4 v = ((const float4*)x)[idx];
        union { uint2 u; __half2 h[2]; } r;
        r.h[0] = __floats2half2_rn(d * v.x, d * v.y);
        r.h[1] = __floats2half2_rn(d * v.z, d * v.w);
        ((uint2*)xh)[idx] = r.u;
    }
}

// ---------- hop 1: y1h[i] = fp16( dinv[i]^2 * (sum_j xh[j] + xh[i]) ) ----------
// 1 wave per node; 4 edge-slots (sub) x 16 feature-lanes (q, 8 fp16 each).
__global__ __launch_bounds__(512) void hop1_kernel(const __half* __restrict__ xh,
                                                   const float* __restrict__ dinv,
                                                   const int* __restrict__ row_ptr,
                                                   const int* __restrict__ csr,
                                                   __half* __restrict__ y1h, int N) {
    const int tid = threadIdx.x;
    const int w = tid >> 6, lane = tid & 63;
    const int i = blockIdx.x * 8 + w;
    if (i >= N) return;                           // wave-uniform; no barriers
    const int sub = lane >> 4;
    const int q = lane & 15;
    const uint4* X = (const uint4*)xh;

    float acc[8] = {0.f, 0.f, 0.f, 0.f, 0.f, 0.f, 0.f, 0.f};
    int ks = row_ptr[i], ke = row_ptr[i + 1];
    int k = ks;
    for (; k + 8 <= ke; k += 8) {                 // 2 x 16B loads in flight per lane
        int j0 = csr[k + sub];
        int j1 = csr[k + 4 + sub];
        uint4 v0 = X[(size_t)j0 * RQ + q];
        uint4 v1 = X[(size_t)j1 * RQ + q];
        accum_h8(acc, v0);
        accum_h8(acc, v1);
    }
    for (; k + 4 <= ke; k += 4) {
        int j = csr[k + sub];
        accum_h8(acc, X[(size_t)j * RQ + q]);
    }
    if (k + sub < ke) {                           // tail 0..3 edges
        int j = csr[k + sub];
        accum_h8(acc, X[(size_t)j * RQ + q]);
    }
    if (sub == 0) accum_h8(acc, X[(size_t)i * RQ + q]);   // self: xh[i] = dinv[i]*x[i]

    #pragma unroll
    for (int t = 0; t < 8; ++t) {
        acc[t] += __shfl_xor(acc[t], 16);
        acc[t] += __shfl_xor(acc[t], 32);
    }

    if (sub == 0) {
        float di = dinv[i];
        float s = di * di;
        union { uint4 u; __half2 h[4]; } r;
        #pragma unroll
        for (int t = 0; t < 4; ++t)
            r.h[t] = __floats2half2_rn(s * acc[2 * t], s * acc[2 * t + 1]);
        ((uint4*)y1h)[(size_t)i * RQ + q] = r.u;
    }
}

// ---------- hop 2 fused with linear + log_softmax ----------
// 512 threads = 8 waves = 8 nodes. Pure unweighted fp16 gather of y1h.
__global__ __launch_bounds__(512) void hop2_cls_kernel(const __half* __restrict__ y1h,
                                                       const float* __restrict__ dinv,
                                                       const int* __restrict__ row_ptr,
                                                       const int* __restrict__ csr,
                                                       const float* __restrict__ W,
                                                       const float* __restrict__ b,
                                                       float* __restrict__ out, int N) {
    __shared__ __align__(16) float Wl[NCLS * WPAD];   // 33 KB, padded rows
    __shared__ float bl[NCLS];
    __shared__ __align__(16) float h[8][NFEAT];

    const int tid = threadIdx.x;
    for (int t = tid; t < NCLS * NFEAT; t += 512) {
        int r = t >> 7, c = t & 127;
        Wl[r * WPAD + c] = W[t];
    }
    if (tid < NCLS) bl[tid] = b[tid];

    const int w = tid >> 6, lane = tid & 63;
    const int i = blockIdx.x * 8 + w;
    const int sub = lane >> 4;
    const int q = lane & 15;
    const uint4* Y = (const uint4*)y1h;

    if (i < N) {
        float acc[8] = {0.f, 0.f, 0.f, 0.f, 0.f, 0.f, 0.f, 0.f};
        int ks = row_ptr[i], ke = row_ptr[i + 1];
        int k = ks;
        for (; k + 8 <= ke; k += 8) {
            int j0 = csr[k + sub];
            int j1 = csr[k + 4 + sub];
            uint4 v0 = Y[(size_t)j0 * RQ + q];
            uint4 v1 = Y[(size_t)j1 * RQ + q];
            accum_h8(acc, v0);
            accum_h8(acc, v1);
        }
        for (; k + 4 <= ke; k += 4) {
            int j = csr[k + sub];
            accum_h8(acc, Y[(size_t)j * RQ + q]);
        }
        if (k + sub < ke) {
            int j = csr[k + sub];
            accum_h8(acc, Y[(size_t)j * RQ + q]);
        }
        if (sub == 0) accum_h8(acc, Y[(size_t)i * RQ + q]);   // self term

        #pragma unroll
        for (int t = 0; t < 8; ++t) {
            acc[t] += __shfl_xor(acc[t], 16);
            acc[t] += __shfl_xor(acc[t], 32);
        }

        if (sub == 0) {                            // x2 = dinv[i] * (sum)
            float di = dinv[i];
            float4 r0 = {di * acc[0], di * acc[1], di * acc[2], di * acc[3]};
            float4 r1 = {di * acc[4], di * acc[5], di * acc[6], di * acc[7]};
            ((float4*)h[w])[2 * q]     = r0;
            ((float4*)h[w])[2 * q + 1] = r1;
        }
    }
    __syncthreads();

    if (i < N) {
        float dot = bl[lane];
        const float4* hr = (const float4*)h[w];                  // broadcast
        const float4* wr = (const float4*)(Wl + lane * WPAD);    // stride 132: clean banking
        #pragma unroll
        for (int t = 0; t < NFEAT / 4; ++t) {
            float4 hv = hr[t], wv = wr[t];
            dot = fmaf(hv.x, wv.x, dot); dot = fmaf(hv.y, wv.y, dot);
            dot = fmaf(hv.z, wv.z, dot); dot = fmaf(hv.w, wv.w, dot);
        }
        float m = dot;
        for (int o = 32; o > 0; o >>= 1) m = fmaxf(m, __shfl_xor(m, o));
        float ex = __expf(dot - m);
        float se = ex;
        for (int o = 32; o > 0; o >>= 1) se += __shfl_xor(se, o);
        out[(size_t)i * NCLS + lane] = dot - m - logf(se);
    }
}

// ---------- launch ----------

static inline size_t align256(size_t v) { return (v + 255) & ~(size_t)255; }

extern "C" void kernel_launch(void* const* d_in, const int* in_sizes, int n_in,
                              void* d_out, int out_size, void* d_ws, size_t ws_size,
                              hipStream_t stream) {
    const float* x  = (const float*)d_in[0];
    const int*   ei = (const int*)d_in[1];
    const float* W  = (const float*)d_in[2];
    const float* b  = (const float*)d_in[3];
    float* out = (float*)d_out;

    const int N = in_sizes[0] / NFEAT;   // 50000
    const int E = in_sizes[1] / 2;       // 800000
    const int* src = ei;
    const int* dst = ei + E;
    const int NB = (N + 255) / 256;      // scan blocks (196 <= 256)

    char* ws = (char*)d_ws;
    size_t o = 0;
    int*    cnt     = (int*)(ws + o);    o += align256((size_t)N * 4);
    float*  dinv    = (float*)(ws + o);  o += align256((size_t)N * 4);
    int*    row_ptr = (int*)(ws + o);    o += align256((size_t)(N + 1) * 4);
    int*    cursor  = (int*)(ws + o);    o += align256((size_t)N * 4);
    int*    bsums   = (int*)(ws + o);    o += align256(256 * 4);
    int*    csr     = (int*)(ws + o);    o += align256((size_t)E * 4);
    __half* xh      = (__half*)(ws + o); o += align256((size_t)N * NFEAT * 2);
    __half* y1h     = (__half*)(ws + o); o += align256((size_t)N * NFEAT * 2);

    const int E4 = (E + 3) / 4;

    hipMemsetAsync(cnt, 0, (size_t)N * 4, stream);
    count_kernel<<<(E4 + 255) / 256, 256, 0, stream>>>(dst, cnt, E);
    scan_local<<<NB, 256, 0, stream>>>(cnt, row_ptr, bsums, N);
    scan_bsums<<<1, 256, 0, stream>>>(bsums, NB);
    scan_finalize<<<NB, 256, 0, stream>>>(cnt, bsums, row_ptr, cursor, dinv, N);
    scatter_kernel<<<(E4 + 255) / 256, 256, 0, stream>>>(src, dst, cursor, csr, E);
    prep_kernel<<<(N * 32 + 255) / 256, 256, 0, stream>>>(x, dinv, xh, N * 32);
    hop1_kernel<<<(N + 7) / 8, 512, 0, stream>>>(xh, dinv, row_ptr, csr, y1h, N);
    hop2_cls_kernel<<<(N + 7) / 8, 512, 0, stream>>>(y1h, dinv, row_ptr, csr, W, b, out, N);
}